// Round 5
// baseline (1726.798 us; speedup 1.0000x reference)
//
#include <hip/hip_runtime.h>
#include <cstdint>
#include <cstddef>

// Problem constants
#define BB   64
#define NN   197
#define CC   768
#define HH   12
#define THD  16          // TOTAL_HEADS
#define DD   64
#define MROWS (BB*NN)    // 12608
#define QKVN (THD*DD)    // 1024
#define SCALE_ 0.125f

typedef unsigned short u16;

__device__ __forceinline__ float bf2f(u16 u) {
  union { unsigned int i; float f; } x; x.i = ((unsigned int)u) << 16; return x.f;
}
__device__ __forceinline__ u16 f2bf(float f) {
  unsigned int x = __builtin_bit_cast(unsigned int, f);
  unsigned int r = (x + 0x7fffu + ((x >> 16) & 1u)) >> 16;   // RNE
  return (u16)r;
}

// ---------------- plain tiled GEMM: C[M,N] = A[M,K] @ B[K,N] + bias ----------
// A,B,bias f32; C bf16 (write_bf16=1) or f32 (write_bf16=0). 64x64 tile,
// BK=16, 256 threads as 16x16, 4x4 per thread. Correct-by-construction.
__global__ __launch_bounds__(256) void k_gemm_nn(const float* __restrict__ A,
                                                 const float* __restrict__ B,
                                                 const float* __restrict__ bias,
                                                 void* __restrict__ Cout,
                                                 int M, int N, int K,
                                                 int write_bf16) {
  __shared__ float As[64][17];
  __shared__ float Bs[16][65];
  int t = threadIdx.x;
  int ti = t >> 4, tj = t & 15;
  int m0 = blockIdx.y * 64, n0 = blockIdx.x * 64;

  float acc[4][4];
#pragma unroll
  for (int i = 0; i < 4; i++)
#pragma unroll
    for (int j = 0; j < 4; j++) acc[i][j] = 0.f;

  int ar = t >> 2, ak = (t & 3) * 4;     // A stage: 64 rows x 16 k
  int bk = t >> 4, bc = (t & 15) * 4;    // B stage: 16 k x 64 cols

  for (int k0 = 0; k0 < K; k0 += 16) {
    int ga = m0 + ar;
    bool av_ok = (ga < M);
    const float* ap = A + (size_t)(av_ok ? ga : 0) * K + k0 + ak;
#pragma unroll
    for (int q = 0; q < 4; q++) As[ar][ak + q] = av_ok ? ap[q] : 0.f;
    const float* bp = B + (size_t)(k0 + bk) * N + n0 + bc;
#pragma unroll
    for (int q = 0; q < 4; q++) Bs[bk][bc + q] = bp[q];
    __syncthreads();
#pragma unroll
    for (int kk = 0; kk < 16; kk++) {
      float av[4], bv[4];
#pragma unroll
      for (int i = 0; i < 4; i++) av[i] = As[ti * 4 + i][kk];
#pragma unroll
      for (int j = 0; j < 4; j++) bv[j] = Bs[kk][tj * 4 + j];
#pragma unroll
      for (int i = 0; i < 4; i++)
#pragma unroll
        for (int j = 0; j < 4; j++) acc[i][j] += av[i] * bv[j];
    }
    __syncthreads();
  }
  u16*   Cb = (u16*)Cout;
  float* Cf = (float*)Cout;
#pragma unroll
  for (int i = 0; i < 4; i++) {
    int gm = m0 + ti * 4 + i;
    if (gm >= M) continue;
#pragma unroll
    for (int j = 0; j < 4; j++) {
      int gn = n0 + tj * 4 + j;
      float v = acc[i][j] + bias[gn];
      if (write_bf16) Cb[(size_t)gm * N + gn] = f2bf(v);
      else            Cf[(size_t)gm * N + gn] = v;
    }
  }
}

// ---------------- middle, maximally naive: one block per (b, n) query row ---
// logits (mask-mix inlined from masks) -> relu -> head-proj -> two-pass
// softmax -> PV. qkv bf16, everything else f32. Writes aout f32 (b,n,H*D).
__global__ __launch_bounds__(256) void k_attn2(const u16* __restrict__ qkv,
                                               const float* __restrict__ masks,
                                               const float* __restrict__ mproj,
                                               const float* __restrict__ mbase,
                                               const float* __restrict__ hpw,
                                               const float* __restrict__ hpb,
                                               float* __restrict__ aout) {
  __shared__ float q2[128];        // q heads 0..1 for this row n
  __shared__ float S[12][200];     // logits, then P
  __shared__ float hpw_s[144], hpb_s[12], mp_s[36], mb_s[12];

  int t = threadIdx.x;
  int n = blockIdx.x, b = blockIdx.y;

  if (t < 144) hpw_s[t] = hpw[t];
  if (t < 36) mp_s[t] = mproj[t];
  if (t < 12) { hpb_s[t] = hpb[t]; mb_s[t] = mbase[t]; }
  if (t < 128) q2[t] = bf2f(qkv[(size_t)(b * NN + n) * QKVN + t]);
  __syncthreads();

  if (t < NN) {   // one m (key row) per thread
    int m = t;
    const u16* krow = qkv + (size_t)(b * NN + m) * QKVN + 2 * DD;  // heads 2,3
    float d0 = 0.f, d1 = 0.f;
    for (int d = 0; d < 64; d++) {
      d0 += q2[d] * bf2f(krow[d]);
      d1 += q2[64 + d] * bf2f(krow[64 + d]);
    }
    float att0 = d0 * SCALE_, att1 = d1 * SCALE_;
    const float* mk = masks + (size_t)(n * NN + m) * 3;
    float l0 = mk[0], l1 = mk[1], l2 = mk[2];
    float pre[12];
#pragma unroll
    for (int h = 0; h < 12; h++) {
      float w = mb_s[h] + l0 * mp_s[h] + l1 * mp_s[12 + h] + l2 * mp_s[24 + h];
      float vv = (h < 6 ? att0 : att1) * w;
      pre[h] = vv > 0.f ? vv : 0.f;
    }
#pragma unroll
    for (int h2 = 0; h2 < 12; h2++) {
      float s = hpb_s[h2];
#pragma unroll
      for (int h = 0; h < 12; h++) s += pre[h] * hpw_s[h * 12 + h2];
      S[h2][m] = s;
    }
  }
  __syncthreads();

  {  // two-pass softmax: head g handled by 16-lane group
    int g = t >> 4, l16 = t & 15;
    if (g < 12) {
      float mx = -1e30f;
      for (int m = l16; m < NN; m += 16) mx = fmaxf(mx, S[g][m]);
#pragma unroll
      for (int off = 8; off; off >>= 1) mx = fmaxf(mx, __shfl_xor(mx, off, 16));
      float sum = 0.f;
      for (int m = l16; m < NN; m += 16) {
        float e = __expf(S[g][m] - mx);
        S[g][m] = e;
        sum += e;
      }
#pragma unroll
      for (int off = 8; off; off >>= 1) sum += __shfl_xor(sum, off, 16);
      float inv = 1.f / sum;
      for (int m = l16; m < NN; m += 16) S[g][m] *= inv;
    }
  }
  __syncthreads();

  // PV: out[h,d] = sum_m P[h][m] * v[m][h,d];  c = h*64+d, 3 c's per thread
#pragma unroll
  for (int rep = 0; rep < 3; rep++) {
    int c = rep * 256 + t;
    int h = c >> 6, d = c & 63;
    float o = 0.f;
    const u16* vp = qkv + (size_t)b * NN * QKVN + (4 + h) * DD + d;
    for (int m = 0; m < NN; m++) o += S[h][m] * bf2f(vp[(size_t)m * QKVN]);
    aout[(size_t)(b * NN + n) * CC + c] = o;
  }
}

extern "C" void kernel_launch(void* const* d_in, const int* in_sizes, int n_in,
                              void* d_out, int out_size, void* d_ws, size_t ws_size,
                              hipStream_t stream) {
  const float* x     = (const float*)d_in[0];
  const float* qkv_w = (const float*)d_in[1];
  const float* qkv_b = (const float*)d_in[2];
  const float* masks = (const float*)d_in[3];
  const float* mproj = (const float*)d_in[4];
  const float* mbase = (const float*)d_in[5];
  const float* hpw   = (const float*)d_in[6];
  const float* hpb   = (const float*)d_in[7];
  const float* projw = (const float*)d_in[8];
  const float* projb = (const float*)d_in[9];

  char* ws = (char*)d_ws;
  size_t off = 0;
  auto alloc = [&](size_t bytes) {
    char* p = ws + off; off = (off + bytes + 255) & ~(size_t)255; return p;
  };
  u16*   qkv  = (u16*)  alloc((size_t)MROWS * QKVN * 2);   // 25.8 MB bf16
  float* aout = (float*)alloc((size_t)MROWS * CC * 4);     // 38.7 MB f32

  // qkv = x @ qkv_w + qkv_b   (M=12608, N=1024, K=768), bf16 intermediate
  k_gemm_nn<<<dim3(QKVN / 64, MROWS / 64), 256, 0, stream>>>(
      x, qkv_w, qkv_b, qkv, MROWS, QKVN, CC, 1);
  // middle
  k_attn2<<<dim3(NN, BB), 256, 0, stream>>>(qkv, masks, mproj, mbase, hpw, hpb, aout);
  // out = aout @ proj_w + proj_b  -> FLOAT32 output (the R5 experiment)
  k_gemm_nn<<<dim3(CC / 64, MROWS / 64), 256, 0, stream>>>(
      aout, projw, projb, d_out, MROWS, CC, CC, 0);
}

// Round 6
// 494.332 us; speedup vs baseline: 3.4932x; 3.4932x over previous
//
#include <hip/hip_runtime.h>
#include <cstdint>
#include <cstddef>

// Problem constants
#define BB   64
#define NN   197
#define CC   768
#define HH   12
#define THD  16          // TOTAL_HEADS
#define DD   64
#define MROWS (BB*NN)    // 12608
#define QKVN (THD*DD)    // 1024
#define SCALE_ 0.125f

typedef unsigned short u16;
typedef __attribute__((ext_vector_type(4))) float f32x4;
typedef __attribute__((ext_vector_type(8))) short s16x8;
typedef __attribute__((address_space(1))) unsigned int as1_u32;
typedef __attribute__((address_space(3))) unsigned int as3_u32;

__device__ __forceinline__ float bf2f(u16 u) {
  union { unsigned int i; float f; } x; x.i = ((unsigned int)u) << 16; return x.f;
}
__device__ __forceinline__ u16 f2bf(float f) {
  unsigned int x = __builtin_bit_cast(unsigned int, f);
  unsigned int r = (x + 0x7fffu + ((x >> 16) & 1u)) >> 16;   // RNE
  return (u16)r;
}
__device__ __forceinline__ void gl_lds16(const u16* g, u16* l) {
  __builtin_amdgcn_global_load_lds((const as1_u32*)g, (as3_u32*)l, 16, 0, 0);
}

// ---------------- x (f32) -> bf16, 8 elems/thread ---------------------------
__global__ __launch_bounds__(256) void k_cvt_x(const float* __restrict__ src,
                                               u16* __restrict__ dst, int n8) {
  int i = blockIdx.x * 256 + threadIdx.x;
  if (i >= n8) return;
  const float4* s = (const float4*)src;
  float4 a = s[2 * i], b = s[2 * i + 1];
  ushort4 lo, hi;
  lo.x = f2bf(a.x); lo.y = f2bf(a.y); lo.z = f2bf(a.z); lo.w = f2bf(a.w);
  hi.x = f2bf(b.x); hi.y = f2bf(b.y); hi.z = f2bf(b.z); hi.w = f2bf(b.w);
  ((ushort4*)dst)[2 * i] = lo;
  ((ushort4*)dst)[2 * i + 1] = hi;
}

// ---------------- weight transpose+convert f32 (R,Ccol) -> bf16 (Ccol,R) ----
__global__ __launch_bounds__(256) void k_transpose(const float* __restrict__ in,
                                                   u16* __restrict__ out,
                                                   int R, int Ccol) {
  __shared__ u16 tile[32][33];
  int c0 = blockIdx.x * 32, r0 = blockIdx.y * 32;
  int tx = threadIdx.x & 31, ty = threadIdx.x >> 5;
#pragma unroll
  for (int i = 0; i < 32; i += 8) {
    int r = r0 + ty + i, c = c0 + tx;
    tile[ty + i][tx] = (r < R && c < Ccol) ? f2bf(in[(size_t)r * Ccol + c]) : (u16)0;
  }
  __syncthreads();
#pragma unroll
  for (int i = 0; i < 32; i += 8) {
    int cc = c0 + ty + i, rr = r0 + tx;
    if (cc < Ccol && rr < R) out[(size_t)cc * R + rr] = tile[tx][ty + i];
  }
}

// ---------------- mask weights: mw[n,m,h] = masks@mask_proj + base (f32) ----
__global__ __launch_bounds__(256) void k_maskw(const float* __restrict__ masks,
                                               const float* __restrict__ mproj,
                                               const float* __restrict__ mbase,
                                               float* __restrict__ mw) {
  __shared__ float proj_s[3][12];
  __shared__ float base_s[12];
  int t = threadIdx.x;
  if (t < 36) proj_s[t / 12][t % 12] = mproj[t];
  if (t < 12) base_s[t] = mbase[t];
  __syncthreads();
  int id = blockIdx.x * 256 + t;
  if (id >= NN * NN) return;
  float m0v = masks[id * 3 + 0];
  float m1v = masks[id * 3 + 1];
  float m2v = masks[id * 3 + 2];
  float o[12];
#pragma unroll
  for (int h = 0; h < 12; h++)
    o[h] = base_s[h] + m0v * proj_s[0][h] + m1v * proj_s[1][h] + m2v * proj_s[2][h];
  float* dst = mw + (size_t)id * 12;
#pragma unroll
  for (int j = 0; j < 3; j++) {
    f32x4 v; v.x = o[4*j]; v.y = o[4*j+1]; v.z = o[4*j+2]; v.w = o[4*j+3];
    *(f32x4*)(dst + 4 * j) = v;
  }
}

// ---------------- bf16 MFMA GEMM: C[M,N] = A[M,K] * Bt[N,K]^T + bias --------
// 128x128 tile, 4 waves (2x2), 16x16x32 MFMA, global_load_lds width-16.
// C written bf16 (write_bf16=1) or f32 (=0).
__global__ __launch_bounds__(256) void k_gemm_bt(const u16* __restrict__ A,
                                                 const u16* __restrict__ Bt,
                                                 const float* __restrict__ bias,
                                                 void* __restrict__ Cout,
                                                 int M, int Nn, int K,
                                                 int write_bf16) {
  __shared__ u16 As[128 * 32];
  __shared__ u16 Bs[128 * 32];
  int t = threadIdx.x;
  int w = t >> 6, lane = t & 63;
  int m0 = blockIdx.y * 128, n0 = blockIdx.x * 128;
  int wm = w >> 1, wn = w & 1;

  f32x4 acc[4][4];
#pragma unroll
  for (int i = 0; i < 4; i++)
#pragma unroll
    for (int j = 0; j < 4; j++)
#pragma unroll
      for (int e = 0; e < 4; e++) acc[i][j][e] = 0.f;

  int lrow4 = lane >> 2;       // 0..15
  int lkc = (lane & 3) * 8;    // 0,8,16,24

  for (int k0 = 0; k0 < K; k0 += 32) {
#pragma unroll
    for (int rc = 0; rc < 2; rc++) {
      int c = w + rc * 4;                 // chunk 0..7 => rows c*16..c*16+15
      int row = c * 16 + lrow4;
      int ga = m0 + row; if (ga >= M) ga = M - 1;
      gl_lds16(A + (size_t)ga * K + k0 + lkc, &As[c * 512]);
      gl_lds16(Bt + (size_t)(n0 + row) * K + k0 + lkc, &Bs[c * 512]);
    }
    __syncthreads();
    int r16 = lane & 15, k8 = (lane >> 4) * 8;
    s16x8 af[4], bfv[4];
#pragma unroll
    for (int s = 0; s < 4; s++) {
      af[s]  = *(const s16x8*)&As[(wm * 64 + s * 16 + r16) * 32 + k8];
      bfv[s] = *(const s16x8*)&Bs[(wn * 64 + s * 16 + r16) * 32 + k8];
    }
#pragma unroll
    for (int sm = 0; sm < 4; sm++)
#pragma unroll
      for (int sn = 0; sn < 4; sn++)
        acc[sm][sn] = __builtin_amdgcn_mfma_f32_16x16x32_bf16(af[sm], bfv[sn], acc[sm][sn], 0, 0, 0);
    __syncthreads();
  }
  // epilogue: C/D layout col=lane&15, row=(lane>>4)*4+i
  u16*   Cb = (u16*)Cout;
  float* Cf = (float*)Cout;
  int quad = lane >> 4, col = lane & 15;
#pragma unroll
  for (int sn = 0; sn < 4; sn++) {
    int gn = n0 + wn * 64 + sn * 16 + col;
    float bv = bias[gn];
#pragma unroll
    for (int sm = 0; sm < 4; sm++) {
      int gmb = m0 + wm * 64 + sm * 16 + quad * 4;
#pragma unroll
      for (int i = 0; i < 4; i++) {
        int gm = gmb + i;
        if (gm < M) {
          float v = acc[sm][sn][i] + bv;
          if (write_bf16) Cb[(size_t)gm * Nn + gn] = f2bf(v);
          else            Cf[(size_t)gm * Nn + gn] = v;
        }
      }
    }
  }
}

// ---------------- fused middle: logits -> mask-mix -> relu -> head-proj ->
//                  online softmax -> PV.  One block per (b, 8 n-rows). -------
__global__ __launch_bounds__(256) void k_attn(const u16* __restrict__ qkv,
                                              const float* __restrict__ mw,
                                              const float* __restrict__ hpw,
                                              const float* __restrict__ hpb,
                                              u16* __restrict__ aout) {
  __shared__ float q_s[8 * 132];          // 8 rows x 128 (g0|g1), pad->132
  __shared__ float k_s[2 * 32 * 68];      // [g][mt][d], pad 64->68
  __shared__ float s_s[96 * 36];          // [(nt*12+h)][mt], pad 32->36
  __shared__ float m_s[96], l_s[96], al_s[96];
  __shared__ float hpw_s[12][12];
  __shared__ float hpb_s[12];

  int t = threadIdx.x;
  int b = blockIdx.y;
  int n0 = blockIdx.x * 8;

  if (t < 144) hpw_s[t / 12][t % 12] = hpw[t];
  if (t < 12) hpb_s[t] = hpb[t];
  if (t < 96) { m_s[t] = -1e30f; l_s[t] = 0.f; }

  {  // load q rows (heads 0..1 are contiguous cols 0..127 of qkv row)
    int idx = t * 4;
    int nt = idx >> 7, c = idx & 127;
    int n = n0 + nt; if (n > NN - 1) n = NN - 1;
    ushort4 u = *(const ushort4*)(qkv + (size_t)(b * NN + n) * QKVN + c);
    float* dst = &q_s[nt * 132 + c];
    dst[0] = bf2f(u.x); dst[1] = bf2f(u.y); dst[2] = bf2f(u.z); dst[3] = bf2f(u.w);
  }
  __syncthreads();

  int ch = t >> 4;             // phase-C head (valid < 12)
  int cd0 = (t & 15) * 4;      // phase-C d offset (4 d's)
  float o[8][4];
#pragma unroll
  for (int i = 0; i < 8; i++)
#pragma unroll
    for (int j = 0; j < 4; j++) o[i][j] = 0.f;

  int ant = t & 7, amt = t >> 3;          // phase-A mapping
  int an = n0 + ant; if (an > NN - 1) an = NN - 1;

  for (int m0 = 0; m0 < NN; m0 += 32) {
    {  // stage k tile: [g][mt][0..63]
      int p = t >> 2;                     // 0..63
      int g = p >> 5, mt = p & 31;
      int d0 = (t & 3) * 16;
      int m = m0 + mt; if (m > NN - 1) m = NN - 1;
      const ushort4* s4 = (const ushort4*)(qkv + (size_t)(b * NN + m) * QKVN + 2 * DD + g * DD + d0);
      float* dst = &k_s[(g * 32 + mt) * 68 + d0];
#pragma unroll
      for (int j = 0; j < 4; j++) {
        ushort4 u = s4[j];
        dst[4*j+0] = bf2f(u.x); dst[4*j+1] = bf2f(u.y);
        dst[4*j+2] = bf2f(u.z); dst[4*j+3] = bf2f(u.w);
      }
    }
    __syncthreads();

    {  // phase A: logits + mask-mix + relu + head-proj -> s_s
      int m = m0 + amt;
      bool mvalid = (m < NN);
      int mc = mvalid ? m : NN - 1;
      float att[2];
#pragma unroll
      for (int g = 0; g < 2; g++) {
        const f32x4* qa = (const f32x4*)&q_s[ant * 132 + g * 64];
        const f32x4* ka = (const f32x4*)&k_s[(g * 32 + amt) * 68];
        float dot = 0.f;
#pragma unroll
        for (int j = 0; j < 16; j++) {
          f32x4 qv = qa[j], kv = ka[j];
          dot += qv.x * kv.x + qv.y * kv.y + qv.z * kv.z + qv.w * kv.w;
        }
        att[g] = dot * SCALE_;
      }
      const float* mwp = mw + ((size_t)an * NN + mc) * 12;
      float pre[12];
#pragma unroll
      for (int j = 0; j < 3; j++) {
        f32x4 m4 = *(const f32x4*)(mwp + j * 4);
        pre[4*j+0] = m4.x; pre[4*j+1] = m4.y; pre[4*j+2] = m4.z; pre[4*j+3] = m4.w;
      }
#pragma unroll
      for (int h = 0; h < 12; h++) {
        float v = att[h / 6] * pre[h];
        pre[h] = v > 0.f ? v : 0.f;
      }
#pragma unroll
      for (int h2 = 0; h2 < 12; h2++) {
        float s = hpb_s[h2];
#pragma unroll
        for (int h = 0; h < 12; h++) s += pre[h] * hpw_s[h][h2];
        s_s[(ant * 12 + h2) * 36 + amt] = mvalid ? s : -1e30f;
      }
    }
    __syncthreads();

    if (t < 96) {  // phase B: online softmax over this 32-m tile
      float* sp = &s_s[t * 36];
      float mold = m_s[t];
      float mx = mold;
      f32x4 sv[8];
#pragma unroll
      for (int j = 0; j < 8; j++) {
        sv[j] = *(const f32x4*)(sp + 4 * j);
        mx = fmaxf(mx, fmaxf(fmaxf(sv[j].x, sv[j].y), fmaxf(sv[j].z, sv[j].w)));
      }
      float alpha = __expf(mold - mx);
      float sum = 0.f;
#pragma unroll
      for (int j = 0; j < 8; j++) {
        f32x4 p;
        p.x = __expf(sv[j].x - mx); p.y = __expf(sv[j].y - mx);
        p.z = __expf(sv[j].z - mx); p.w = __expf(sv[j].w - mx);
        sum += p.x + p.y + p.z + p.w;
        *(f32x4*)(sp + 4 * j) = p;
      }
      l_s[t] = l_s[t] * alpha + sum;
      m_s[t] = mx;
      al_s[t] = alpha;
    }
    __syncthreads();

    if (ch < 12) {  // phase C: o = o*alpha + P*V
#pragma unroll
      for (int nt = 0; nt < 8; nt++) {
        float a = al_s[nt * 12 + ch];
#pragma unroll
        for (int j = 0; j < 4; j++) o[nt][j] *= a;
      }
#pragma unroll
      for (int mc4 = 0; mc4 < 8; mc4++) {
        float vv[4][4];
#pragma unroll
        for (int i = 0; i < 4; i++) {
          int m = m0 + mc4 * 4 + i; if (m > NN - 1) m = NN - 1;
          ushort4 u = *(const ushort4*)(qkv + (size_t)(b * NN + m) * QKVN + 4 * DD + ch * DD + cd0);
          vv[i][0] = bf2f(u.x); vv[i][1] = bf2f(u.y); vv[i][2] = bf2f(u.z); vv[i][3] = bf2f(u.w);
        }
#pragma unroll
        for (int nt = 0; nt < 8; nt++) {
          f32x4 p4 = *(const f32x4*)&s_s[(nt * 12 + ch) * 36 + mc4 * 4];
#pragma unroll
          for (int i = 0; i < 4; i++)
#pragma unroll
            for (int j = 0; j < 4; j++)
              o[nt][j] += p4[i] * vv[i][j];
        }
      }
    }
    __syncthreads();
  }

  if (ch < 12) {  // normalize + write attn_out[b,n, h*64+d] (bf16)
#pragma unroll
    for (int nt = 0; nt < 8; nt++) {
      int n = n0 + nt;
      if (n < NN) {
        float inv = 1.f / l_s[nt * 12 + ch];
        ushort4 u;
        u.x = f2bf(o[nt][0] * inv); u.y = f2bf(o[nt][1] * inv);
        u.z = f2bf(o[nt][2] * inv); u.w = f2bf(o[nt][3] * inv);
        *(ushort4*)(aout + (size_t)(b * NN + n) * CC + ch * DD + cd0) = u;
      }
    }
  }
}

extern "C" void kernel_launch(void* const* d_in, const int* in_sizes, int n_in,
                              void* d_out, int out_size, void* d_ws, size_t ws_size,
                              hipStream_t stream) {
  const float* x     = (const float*)d_in[0];
  const float* qkv_w = (const float*)d_in[1];
  const float* qkv_b = (const float*)d_in[2];
  const float* masks = (const float*)d_in[3];
  const float* mproj = (const float*)d_in[4];
  const float* mbase = (const float*)d_in[5];
  const float* hpw   = (const float*)d_in[6];
  const float* hpb   = (const float*)d_in[7];
  const float* projw = (const float*)d_in[8];
  const float* projb = (const float*)d_in[9];

  char* ws = (char*)d_ws;
  size_t off = 0;
  auto alloc = [&](size_t bytes) {
    char* p = ws + off; off = (off + bytes + 255) & ~(size_t)255; return p;
  };
  u16*   xbf  = (u16*)  alloc((size_t)MROWS * CC * 2);     // 19.4 MB
  u16*   qkv  = (u16*)  alloc((size_t)MROWS * QKVN * 2);   // 25.8 MB
  u16*   aout = (u16*)  alloc((size_t)MROWS * CC * 2);     // 19.4 MB
  float* mw   = (float*)alloc((size_t)NN * NN * 12 * 4);   //  1.9 MB
  u16*   wt1  = (u16*)  alloc((size_t)QKVN * CC * 2);      //  1.6 MB
  u16*   wt2  = (u16*)  alloc((size_t)CC * CC * 2);        //  1.2 MB

  int n8 = MROWS * CC / 8;
  k_cvt_x<<<(n8 + 255) / 256, 256, 0, stream>>>(x, xbf, n8);
  k_transpose<<<dim3(QKVN / 32, CC / 32), 256, 0, stream>>>(qkv_w, wt1, CC, QKVN);
  k_transpose<<<dim3(CC / 32, CC / 32), 256, 0, stream>>>(projw, wt2, CC, CC);
  k_maskw<<<dim3((NN * NN + 255) / 256), 256, 0, stream>>>(masks, mproj, mbase, mw);
  // qkv = x @ qkv_w + qkv_b  (bf16 out)
  k_gemm_bt<<<dim3(QKVN / 128, (MROWS + 127) / 128), 256, 0, stream>>>(
      xbf, wt1, qkv_b, qkv, MROWS, QKVN, CC, 1);
  k_attn<<<dim3((NN + 7) / 8, BB), 256, 0, stream>>>(qkv, mw, hpw, hpb, aout);
  // out = aout @ proj_w + proj_b  (f32 out)
  k_gemm_bt<<<dim3(CC / 128, (MROWS + 127) / 128), 256, 0, stream>>>(
      aout, wt2, projb, d_out, MROWS, CC, CC, 0);
}

// Round 7
// 300.779 us; speedup vs baseline: 5.7411x; 1.6435x over previous
//
#include <hip/hip_runtime.h>
#include <cstdint>
#include <cstddef>

// Problem constants
#define BB   64
#define NN   197
#define CC   768
#define HH   12
#define THD  16          // TOTAL_HEADS
#define DD   64
#define MROWS (BB*NN)    // 12608
#define QKVN (THD*DD)    // 1024
#define SCALE_ 0.125f
#define ATTS 208         // att row stride (f32)
#define KPAD 224         // P row k-padding (7*32)

typedef unsigned short u16;
typedef __attribute__((ext_vector_type(4))) float f32x4;
typedef __attribute__((ext_vector_type(8))) short s16x8;
typedef __attribute__((address_space(1))) unsigned int as1_u32;
typedef __attribute__((address_space(3))) unsigned int as3_u32;

__device__ __forceinline__ float bf2f(u16 u) {
  union { unsigned int i; float f; } x; x.i = ((unsigned int)u) << 16; return x.f;
}
__device__ __forceinline__ u16 f2bf(float f) {
  unsigned int x = __builtin_bit_cast(unsigned int, f);
  unsigned int r = (x + 0x7fffu + ((x >> 16) & 1u)) >> 16;   // RNE
  return (u16)r;
}
__device__ __forceinline__ void gl_lds16(const u16* g, u16* l) {
  __builtin_amdgcn_global_load_lds((const as1_u32*)g, (as3_u32*)l, 16, 0, 0);
}

// ---------------- x (f32) -> bf16, 8 elems/thread ---------------------------
__global__ __launch_bounds__(256) void k_cvt_x(const float* __restrict__ src,
                                               u16* __restrict__ dst, int n8) {
  int i = blockIdx.x * 256 + threadIdx.x;
  if (i >= n8) return;
  const float4* s = (const float4*)src;
  float4 a = s[2 * i], b = s[2 * i + 1];
  ushort4 lo, hi;
  lo.x = f2bf(a.x); lo.y = f2bf(a.y); lo.z = f2bf(a.z); lo.w = f2bf(a.w);
  hi.x = f2bf(b.x); hi.y = f2bf(b.y); hi.z = f2bf(b.z); hi.w = f2bf(b.w);
  ((ushort4*)dst)[2 * i] = lo;
  ((ushort4*)dst)[2 * i + 1] = hi;
}

// ---------------- weight transpose+convert f32 (R,Ccol) -> bf16 (Ccol,R) ----
__global__ __launch_bounds__(256) void k_transpose(const float* __restrict__ in,
                                                   u16* __restrict__ out,
                                                   int R, int Ccol) {
  __shared__ u16 tile[32][33];
  int c0 = blockIdx.x * 32, r0 = blockIdx.y * 32;
  int tx = threadIdx.x & 31, ty = threadIdx.x >> 5;
#pragma unroll
  for (int i = 0; i < 32; i += 8) {
    int r = r0 + ty + i, c = c0 + tx;
    tile[ty + i][tx] = (r < R && c < Ccol) ? f2bf(in[(size_t)r * Ccol + c]) : (u16)0;
  }
  __syncthreads();
#pragma unroll
  for (int i = 0; i < 32; i += 8) {
    int cc = c0 + ty + i, rr = r0 + tx;
    if (cc < Ccol && rr < R) out[(size_t)cc * R + rr] = tile[tx][ty + i];
  }
}

// ---------------- bf16 MFMA GEMM: C[M,N] = A[M,K] * Bt[N,K]^T + bias --------
// 128x128 tile, 4 waves (2x2), 16x16x32 MFMA, global_load_lds width-16.
__global__ __launch_bounds__(256) void k_gemm_bt(const u16* __restrict__ A,
                                                 const u16* __restrict__ Bt,
                                                 const float* __restrict__ bias,
                                                 void* __restrict__ Cout,
                                                 int M, int Nn, int K,
                                                 int write_bf16) {
  __shared__ u16 As[128 * 32];
  __shared__ u16 Bs[128 * 32];
  int t = threadIdx.x;
  int w = t >> 6, lane = t & 63;
  int m0 = blockIdx.y * 128, n0 = blockIdx.x * 128;
  int wm = w >> 1, wn = w & 1;

  f32x4 acc[4][4];
#pragma unroll
  for (int i = 0; i < 4; i++)
#pragma unroll
    for (int j = 0; j < 4; j++)
#pragma unroll
      for (int e = 0; e < 4; e++) acc[i][j][e] = 0.f;

  int lrow4 = lane >> 2;       // 0..15
  int lkc = (lane & 3) * 8;    // 0,8,16,24

  for (int k0 = 0; k0 < K; k0 += 32) {
#pragma unroll
    for (int rc = 0; rc < 2; rc++) {
      int c = w + rc * 4;                 // chunk 0..7 => rows c*16..c*16+15
      int row = c * 16 + lrow4;
      int ga = m0 + row; if (ga >= M) ga = M - 1;
      gl_lds16(A + (size_t)ga * K + k0 + lkc, &As[c * 512]);
      gl_lds16(Bt + (size_t)(n0 + row) * K + k0 + lkc, &Bs[c * 512]);
    }
    __syncthreads();
    int r16 = lane & 15, k8 = (lane >> 4) * 8;
    s16x8 af[4], bfv[4];
#pragma unroll
    for (int s = 0; s < 4; s++) {
      af[s]  = *(const s16x8*)&As[(wm * 64 + s * 16 + r16) * 32 + k8];
      bfv[s] = *(const s16x8*)&Bs[(wn * 64 + s * 16 + r16) * 32 + k8];
    }
#pragma unroll
    for (int sm = 0; sm < 4; sm++)
#pragma unroll
      for (int sn = 0; sn < 4; sn++)
        acc[sm][sn] = __builtin_amdgcn_mfma_f32_16x16x32_bf16(af[sm], bfv[sn], acc[sm][sn], 0, 0, 0);
    __syncthreads();
  }
  // epilogue: C/D layout col=lane&15, row=(lane>>4)*4+i
  u16*   Cb = (u16*)Cout;
  float* Cf = (float*)Cout;
  int quad = lane >> 4, col = lane & 15;
#pragma unroll
  for (int sn = 0; sn < 4; sn++) {
    int gn = n0 + wn * 64 + sn * 16 + col;
    float bv = bias[gn];
#pragma unroll
    for (int sm = 0; sm < 4; sm++) {
      int gmb = m0 + wm * 64 + sm * 16 + quad * 4;
#pragma unroll
      for (int i = 0; i < 4; i++) {
        int gm = gmb + i;
        if (gm < M) {
          float v = acc[sm][sn][i] + bv;
          if (write_bf16) Cb[(size_t)gm * Nn + gn] = f2bf(v);
          else            Cf[(size_t)gm * Nn + gn] = v;
        }
      }
    }
  }
}

// ---------------- QK^T logits via MFMA: att[bg][n][m] = SCALE * q_n . k_m ---
// One block per (n-tile 128, m-tile 128, b*2+g). K=64 (2 k-steps).
__global__ __launch_bounds__(256) void k_qk(const u16* __restrict__ qkv,
                                            float* __restrict__ att) {
  __shared__ u16 As[128 * 32];
  __shared__ u16 Bs[128 * 32];
  int t = threadIdx.x;
  int w = t >> 6, lane = t & 63;
  int bz = blockIdx.z, b = bz >> 1, g = bz & 1;
  int n0 = blockIdx.x * 128;     // Q rows
  int m0 = blockIdx.y * 128;     // K rows
  int wm = w >> 1, wn = w & 1;

  f32x4 acc[4][4];
#pragma unroll
  for (int i = 0; i < 4; i++)
#pragma unroll
    for (int j = 0; j < 4; j++)
#pragma unroll
      for (int e = 0; e < 4; e++) acc[i][j][e] = 0.f;

  int lrow4 = lane >> 2, lkc = (lane & 3) * 8;

  for (int k0 = 0; k0 < 64; k0 += 32) {
#pragma unroll
    for (int rc = 0; rc < 2; rc++) {
      int c = w + rc * 4;
      int row = c * 16 + lrow4;
      int nq = n0 + row; if (nq > NN - 1) nq = NN - 1;
      int mk = m0 + row; if (mk > NN - 1) mk = NN - 1;
      gl_lds16(qkv + (size_t)(b * NN + nq) * QKVN + g * DD + k0 + lkc, &As[c * 512]);
      gl_lds16(qkv + (size_t)(b * NN + mk) * QKVN + 2 * DD + g * DD + k0 + lkc, &Bs[c * 512]);
    }
    __syncthreads();
    int r16 = lane & 15, k8 = (lane >> 4) * 8;
    s16x8 af[4], bfv[4];
#pragma unroll
    for (int s = 0; s < 4; s++) {
      af[s]  = *(const s16x8*)&As[(wm * 64 + s * 16 + r16) * 32 + k8];
      bfv[s] = *(const s16x8*)&Bs[(wn * 64 + s * 16 + r16) * 32 + k8];
    }
#pragma unroll
    for (int sm = 0; sm < 4; sm++)
#pragma unroll
      for (int sn = 0; sn < 4; sn++)
        acc[sm][sn] = __builtin_amdgcn_mfma_f32_16x16x32_bf16(af[sm], bfv[sn], acc[sm][sn], 0, 0, 0);
    __syncthreads();
  }
  int quad = lane >> 4, col = lane & 15;
#pragma unroll
  for (int sn = 0; sn < 4; sn++) {
    int gn = m0 + wn * 64 + sn * 16 + col;          // key index m
#pragma unroll
    for (int sm = 0; sm < 4; sm++) {
      int gmb = n0 + wm * 64 + sm * 16 + quad * 4;  // query index n
#pragma unroll
      for (int i = 0; i < 4; i++) {
        int gm = gmb + i;
        if (gm < NN && gn < NN)
          att[((size_t)bz * NN + gm) * ATTS + gn] = acc[sm][sn][i] * SCALE_;
      }
    }
  }
}

// ---------------- per (b,n): mask-mix + relu + head-proj + softmax -> P -----
// P[b][h][n][KPAD] bf16, zero-padded for m in [197,224).
__global__ __launch_bounds__(256) void k_softmax_p(const float* __restrict__ att,
                                                   const float* __restrict__ masks,
                                                   const float* __restrict__ mproj,
                                                   const float* __restrict__ mbase,
                                                   const float* __restrict__ hpw,
                                                   const float* __restrict__ hpb,
                                                   u16* __restrict__ P) {
  __shared__ float S[12][200];
  __shared__ float hpw_s[144], hpb_s[12], mp_s[36], mb_s[12];
  int t = threadIdx.x;
  int n = blockIdx.x, b = blockIdx.y;

  if (t < 144) hpw_s[t] = hpw[t];
  if (t < 36) mp_s[t] = mproj[t];
  if (t < 12) { hpb_s[t] = hpb[t]; mb_s[t] = mbase[t]; }
  __syncthreads();

  if (t < NN) {
    int m = t;
    float a0 = att[((size_t)(b * 2 + 0) * NN + n) * ATTS + m];
    float a1 = att[((size_t)(b * 2 + 1) * NN + n) * ATTS + m];
    const float* mk = masks + ((size_t)n * NN + m) * 3;
    float l0 = mk[0], l1 = mk[1], l2 = mk[2];
    float pre[12];
#pragma unroll
    for (int h = 0; h < 12; h++) {
      float wgt = mb_s[h] + l0 * mp_s[h] + l1 * mp_s[12 + h] + l2 * mp_s[24 + h];
      float v = (h < 6 ? a0 : a1) * wgt;
      pre[h] = v > 0.f ? v : 0.f;
    }
#pragma unroll
    for (int h2 = 0; h2 < 12; h2++) {
      float s = hpb_s[h2];
#pragma unroll
      for (int h = 0; h < 12; h++) s += pre[h] * hpw_s[h * 12 + h2];
      S[h2][m] = s;
    }
  }
  __syncthreads();

  {  // softmax per head, 16-lane groups (R5-verified pattern)
    int g = t >> 4, l16 = t & 15;
    if (g < 12) {
      float mx = -1e30f;
      for (int m = l16; m < NN; m += 16) mx = fmaxf(mx, S[g][m]);
#pragma unroll
      for (int off = 8; off; off >>= 1) mx = fmaxf(mx, __shfl_xor(mx, off, 16));
      float sum = 0.f;
      for (int m = l16; m < NN; m += 16) {
        float e = __expf(S[g][m] - mx);
        S[g][m] = e;
        sum += e;
      }
#pragma unroll
      for (int off = 8; off; off >>= 1) sum += __shfl_xor(sum, off, 16);
      float inv = 1.f / sum;
      for (int m = l16; m < NN; m += 16) S[g][m] *= inv;
    }
  }
  __syncthreads();

  // write P rows (bf16), zero tail m in [197,224)
  for (int c4 = t; c4 < 12 * KPAD / 4; c4 += 256) {
    int idx = c4 * 4;
    int h = idx / KPAD, m = idx - h * KPAD;
    ushort4 u;
    u.x = f2bf(m + 0 < NN ? S[h][m + 0] : 0.f);
    u.y = f2bf(m + 1 < NN ? S[h][m + 1] : 0.f);
    u.z = f2bf(m + 2 < NN ? S[h][m + 2] : 0.f);
    u.w = f2bf(m + 3 < NN ? S[h][m + 3] : 0.f);
    *(ushort4*)(P + ((size_t)(b * HH + h) * NN + n) * KPAD + m) = u;
  }
}

// ---------------- PV via MFMA: O[b,n,h,d] = sum_m P[b,h,n,m] V[b,m,h,d] -----
// One block per (n-tile 128, b*12+h). M=197(n) N=64(d) K=224(m).
// A = P (k-contiguous, gl_lds16); B = V transposed into LDS at staging.
__global__ __launch_bounds__(256) void k_pv(const u16* __restrict__ P,
                                            const u16* __restrict__ qkv,
                                            u16* __restrict__ aout) {
  __shared__ u16 As[128 * 32];     // P rows [n][32 m]
  __shared__ u16 Bs[64 * 32];      // VT [d][32 m]
  int t = threadIdx.x;
  int w = t >> 6, lane = t & 63;
  int bh = blockIdx.y, b = bh / HH, h = bh - b * HH;
  int n0 = blockIdx.x * 128;

  f32x4 acc[2][4];
#pragma unroll
  for (int i = 0; i < 2; i++)
#pragma unroll
    for (int j = 0; j < 4; j++)
#pragma unroll
      for (int e = 0; e < 4; e++) acc[i][j][e] = 0.f;

  int lrow4 = lane >> 2, lkc = (lane & 3) * 8;
  int vml = t & 31, vd0 = (t >> 5) * 8;    // B-staging mapping

  for (int k0 = 0; k0 < KPAD; k0 += 32) {
    // A: P rows via gl_lds16 (8 chunks over 4 waves x 2)
#pragma unroll
    for (int rc = 0; rc < 2; rc++) {
      int c = w + rc * 4;
      int row = c * 16 + lrow4;
      int gn = n0 + row; if (gn > NN - 1) gn = NN - 1;
      gl_lds16(P + ((size_t)bh * NN + gn) * KPAD + k0 + lkc, &As[c * 512]);
    }
    // B: V rows -> transposed LDS [d][m]
    {
      int m = k0 + vml;
      u16 v8[8];
      if (m < NN) {
        const ushort4* vp = (const ushort4*)(qkv + (size_t)(b * NN + m) * QKVN + (4 + h) * DD + vd0);
        ushort4 lo = vp[0], hi = vp[1];
        v8[0] = lo.x; v8[1] = lo.y; v8[2] = lo.z; v8[3] = lo.w;
        v8[4] = hi.x; v8[5] = hi.y; v8[6] = hi.z; v8[7] = hi.w;
      } else {
#pragma unroll
        for (int j = 0; j < 8; j++) v8[j] = 0;
      }
#pragma unroll
      for (int j = 0; j < 8; j++) Bs[(vd0 + j) * 32 + vml] = v8[j];
    }
    __syncthreads();
    int r16 = lane & 15, k8 = (lane >> 4) * 8;
    s16x8 af[2], bfv[4];
#pragma unroll
    for (int s = 0; s < 2; s++)
      af[s] = *(const s16x8*)&As[(w * 32 + s * 16 + r16) * 32 + k8];
#pragma unroll
    for (int s = 0; s < 4; s++)
      bfv[s] = *(const s16x8*)&Bs[(s * 16 + r16) * 32 + k8];
#pragma unroll
    for (int sm = 0; sm < 2; sm++)
#pragma unroll
      for (int sn = 0; sn < 4; sn++)
        acc[sm][sn] = __builtin_amdgcn_mfma_f32_16x16x32_bf16(af[sm], bfv[sn], acc[sm][sn], 0, 0, 0);
    __syncthreads();
  }
  int quad = lane >> 4, col = lane & 15;
#pragma unroll
  for (int sn = 0; sn < 4; sn++) {
    int gd = sn * 16 + col;                         // d
#pragma unroll
    for (int sm = 0; sm < 2; sm++) {
      int gnb = n0 + w * 32 + sm * 16 + quad * 4;   // n
#pragma unroll
      for (int i = 0; i < 4; i++) {
        int gn = gnb + i;
        if (gn < NN)
          aout[(size_t)(b * NN + gn) * CC + h * DD + gd] = f2bf(acc[sm][sn][i]);
      }
    }
  }
}

extern "C" void kernel_launch(void* const* d_in, const int* in_sizes, int n_in,
                              void* d_out, int out_size, void* d_ws, size_t ws_size,
                              hipStream_t stream) {
  const float* x     = (const float*)d_in[0];
  const float* qkv_w = (const float*)d_in[1];
  const float* qkv_b = (const float*)d_in[2];
  const float* masks = (const float*)d_in[3];
  const float* mproj = (const float*)d_in[4];
  const float* mbase = (const float*)d_in[5];
  const float* hpw   = (const float*)d_in[6];
  const float* hpb   = (const float*)d_in[7];
  const float* projw = (const float*)d_in[8];
  const float* projb = (const float*)d_in[9];

  char* ws = (char*)d_ws;
  size_t off = 0;
  auto alloc = [&](size_t bytes) {
    char* p = ws + off; off = (off + bytes + 255) & ~(size_t)255; return p;
  };
  // region1: xbf (19.4MB) -> att (21.0MB) -> aout (19.4MB), disjoint lifetimes
  char*  r1   = alloc((size_t)BB * 2 * NN * ATTS * 4);
  u16*   xbf  = (u16*)r1;
  float* att  = (float*)r1;
  u16*   aout = (u16*)r1;
  u16*   qkv  = (u16*)alloc((size_t)MROWS * QKVN * 2);          // 25.8 MB
  u16*   P    = (u16*)alloc((size_t)BB * HH * NN * KPAD * 2);   // 67.8 MB
  u16*   wt1  = (u16*)alloc((size_t)QKVN * CC * 2);             //  1.6 MB
  u16*   wt2  = (u16*)alloc((size_t)CC * CC * 2);               //  1.2 MB

  int n8 = MROWS * CC / 8;
  k_cvt_x<<<(n8 + 255) / 256, 256, 0, stream>>>(x, xbf, n8);
  k_transpose<<<dim3(QKVN / 32, CC / 32), 256, 0, stream>>>(qkv_w, wt1, CC, QKVN);
  k_transpose<<<dim3(CC / 32, CC / 32), 256, 0, stream>>>(projw, wt2, CC, CC);
  // qkv = x @ qkv_w + qkv_b  (bf16 out)
  k_gemm_bt<<<dim3(QKVN / 128, (MROWS + 127) / 128), 256, 0, stream>>>(
      xbf, wt1, qkv_b, qkv, MROWS, QKVN, CC, 1);
  // att[bg][n][m] = SCALE * q.k
  k_qk<<<dim3(2, 2, BB * 2), 256, 0, stream>>>(qkv, att);
  // P[b][h][n][m] (bf16, softmaxed)
  k_softmax_p<<<dim3(NN, BB), 256, 0, stream>>>(att, masks, mproj, mbase, hpw, hpb, P);
  // aout[b][n][h*64+d] = P @ V
  k_pv<<<dim3(2, BB * HH), 256, 0, stream>>>(P, qkv, aout);
  // out = aout @ proj_w + proj_b  (f32 out)
  k_gemm_bt<<<dim3(CC / 128, (MROWS + 127) / 128), 256, 0, stream>>>(
      aout, wt2, projb, d_out, MROWS, CC, CC, 0);
}

// Round 8
// 298.208 us; speedup vs baseline: 5.7906x; 1.0086x over previous
//
#include <hip/hip_runtime.h>
#include <cstdint>
#include <cstddef>

// Problem constants
#define BB   64
#define NN   197
#define CC   768
#define HH   12
#define THD  16          // TOTAL_HEADS
#define DD   64
#define MROWS (BB*NN)    // 12608
#define QKVN (THD*DD)    // 1024
#define SCALE_ 0.125f
#define ATTS 208         // att row stride (f32)
#define KPAD 224         // P row k-padding (7*32)

typedef unsigned short u16;
typedef __attribute__((ext_vector_type(4))) float f32x4;
typedef __attribute__((ext_vector_type(8))) short s16x8;
typedef __attribute__((address_space(1))) unsigned int as1_u32;
typedef __attribute__((address_space(3))) unsigned int as3_u32;

__device__ __forceinline__ float bf2f(u16 u) {
  union { unsigned int i; float f; } x; x.i = ((unsigned int)u) << 16; return x.f;
}
__device__ __forceinline__ u16 f2bf(float f) {
  unsigned int x = __builtin_bit_cast(unsigned int, f);
  unsigned int r = (x + 0x7fffu + ((x >> 16) & 1u)) >> 16;   // RNE
  return (u16)r;
}
__device__ __forceinline__ void gl_lds16(const u16* g, u16* l) {
  __builtin_amdgcn_global_load_lds((const as1_u32*)g, (as3_u32*)l, 16, 0, 0);
}

// ---------------- x (f32) -> bf16, 8 elems/thread ---------------------------
__global__ __launch_bounds__(256) void k_cvt_x(const float* __restrict__ src,
                                               u16* __restrict__ dst, int n8) {
  int i = blockIdx.x * 256 + threadIdx.x;
  if (i >= n8) return;
  const float4* s = (const float4*)src;
  float4 a = s[2 * i], b = s[2 * i + 1];
  ushort4 lo, hi;
  lo.x = f2bf(a.x); lo.y = f2bf(a.y); lo.z = f2bf(a.z); lo.w = f2bf(a.w);
  hi.x = f2bf(b.x); hi.y = f2bf(b.y); hi.z = f2bf(b.z); hi.w = f2bf(b.w);
  ((ushort4*)dst)[2 * i] = lo;
  ((ushort4*)dst)[2 * i + 1] = hi;
}

// ---------------- weight transpose+convert f32 (R,Ccol) -> bf16 (Ccol,R) ----
__global__ __launch_bounds__(256) void k_transpose(const float* __restrict__ in,
                                                   u16* __restrict__ out,
                                                   int R, int Ccol) {
  __shared__ u16 tile[32][33];
  int c0 = blockIdx.x * 32, r0 = blockIdx.y * 32;
  int tx = threadIdx.x & 31, ty = threadIdx.x >> 5;
#pragma unroll
  for (int i = 0; i < 32; i += 8) {
    int r = r0 + ty + i, c = c0 + tx;
    tile[ty + i][tx] = (r < R && c < Ccol) ? f2bf(in[(size_t)r * Ccol + c]) : (u16)0;
  }
  __syncthreads();
#pragma unroll
  for (int i = 0; i < 32; i += 8) {
    int cc = c0 + ty + i, rr = r0 + tx;
    if (cc < Ccol && rr < R) out[(size_t)cc * R + rr] = tile[tx][ty + i];
  }
}

// ---------------- bf16 MFMA GEMM: C[M,N] = A[M,K] * Bt[N,K]^T + bias --------
// 128x128 tile, 4 waves (2x2), 16x16x32 MFMA, BK=64 (two 32-k halves per
// barrier -> 32 MFMA/barrier), global_load_lds width-16.
__global__ __launch_bounds__(256) void k_gemm_bt(const u16* __restrict__ A,
                                                 const u16* __restrict__ Bt,
                                                 const float* __restrict__ bias,
                                                 void* __restrict__ Cout,
                                                 int M, int Nn, int K,
                                                 int write_bf16) {
  __shared__ u16 As[2][128 * 32];
  __shared__ u16 Bs[2][128 * 32];
  int t = threadIdx.x;
  int w = t >> 6, lane = t & 63;
  int m0 = blockIdx.y * 128, n0 = blockIdx.x * 128;
  int wm = w >> 1, wn = w & 1;

  f32x4 acc[4][4];
#pragma unroll
  for (int i = 0; i < 4; i++)
#pragma unroll
    for (int j = 0; j < 4; j++)
#pragma unroll
      for (int e = 0; e < 4; e++) acc[i][j][e] = 0.f;

  int lrow4 = lane >> 2;       // 0..15
  int lkc = (lane & 3) * 8;    // 0,8,16,24

  for (int k0 = 0; k0 < K; k0 += 64) {
#pragma unroll
    for (int half = 0; half < 2; half++) {
      int kk = k0 + half * 32;
#pragma unroll
      for (int rc = 0; rc < 2; rc++) {
        int c = w + rc * 4;                 // chunk 0..7 => rows c*16..c*16+15
        int row = c * 16 + lrow4;
        int ga = m0 + row; if (ga >= M) ga = M - 1;
        gl_lds16(A + (size_t)ga * K + kk + lkc, &As[half][c * 512]);
        gl_lds16(Bt + (size_t)(n0 + row) * K + kk + lkc, &Bs[half][c * 512]);
      }
    }
    __syncthreads();
    int r16 = lane & 15, k8 = (lane >> 4) * 8;
#pragma unroll
    for (int half = 0; half < 2; half++) {
      s16x8 af[4], bfv[4];
#pragma unroll
      for (int s = 0; s < 4; s++) {
        af[s]  = *(const s16x8*)&As[half][(wm * 64 + s * 16 + r16) * 32 + k8];
        bfv[s] = *(const s16x8*)&Bs[half][(wn * 64 + s * 16 + r16) * 32 + k8];
      }
#pragma unroll
      for (int sm = 0; sm < 4; sm++)
#pragma unroll
        for (int sn = 0; sn < 4; sn++)
          acc[sm][sn] = __builtin_amdgcn_mfma_f32_16x16x32_bf16(af[sm], bfv[sn], acc[sm][sn], 0, 0, 0);
    }
    __syncthreads();
  }
  // epilogue: C/D layout col=lane&15, row=(lane>>4)*4+i
  u16*   Cb = (u16*)Cout;
  float* Cf = (float*)Cout;
  int quad = lane >> 4, col = lane & 15;
#pragma unroll
  for (int sn = 0; sn < 4; sn++) {
    int gn = n0 + wn * 64 + sn * 16 + col;
    float bv = bias[gn];
#pragma unroll
    for (int sm = 0; sm < 4; sm++) {
      int gmb = m0 + wm * 64 + sm * 16 + quad * 4;
#pragma unroll
      for (int i = 0; i < 4; i++) {
        int gm = gmb + i;
        if (gm < M) {
          float v = acc[sm][sn][i] + bv;
          if (write_bf16) Cb[(size_t)gm * Nn + gn] = f2bf(v);
          else            Cf[(size_t)gm * Nn + gn] = v;
        }
      }
    }
  }
}

// ---------------- QK^T logits via MFMA: att[bg][n][m] = SCALE * q_n . k_m ---
// One block per (n-tile 128, m-tile 128, b*2+g). K=64: ONE barrier, 32 MFMA.
__global__ __launch_bounds__(256) void k_qk(const u16* __restrict__ qkv,
                                            float* __restrict__ att) {
  __shared__ u16 As[2][128 * 32];
  __shared__ u16 Bs[2][128 * 32];
  int t = threadIdx.x;
  int w = t >> 6, lane = t & 63;
  int bz = blockIdx.z, b = bz >> 1, g = bz & 1;
  int n0 = blockIdx.x * 128;     // Q rows
  int m0 = blockIdx.y * 128;     // K rows
  int wm = w >> 1, wn = w & 1;

  f32x4 acc[4][4];
#pragma unroll
  for (int i = 0; i < 4; i++)
#pragma unroll
    for (int j = 0; j < 4; j++)
#pragma unroll
      for (int e = 0; e < 4; e++) acc[i][j][e] = 0.f;

  int lrow4 = lane >> 2, lkc = (lane & 3) * 8;

#pragma unroll
  for (int half = 0; half < 2; half++) {
    int kk = half * 32;
#pragma unroll
    for (int rc = 0; rc < 2; rc++) {
      int c = w + rc * 4;
      int row = c * 16 + lrow4;
      int nq = n0 + row; if (nq > NN - 1) nq = NN - 1;
      int mk = m0 + row; if (mk > NN - 1) mk = NN - 1;
      gl_lds16(qkv + (size_t)(b * NN + nq) * QKVN + g * DD + kk + lkc, &As[half][c * 512]);
      gl_lds16(qkv + (size_t)(b * NN + mk) * QKVN + 2 * DD + g * DD + kk + lkc, &Bs[half][c * 512]);
    }
  }
  __syncthreads();
  {
    int r16 = lane & 15, k8 = (lane >> 4) * 8;
#pragma unroll
    for (int half = 0; half < 2; half++) {
      s16x8 af[4], bfv[4];
#pragma unroll
      for (int s = 0; s < 4; s++) {
        af[s]  = *(const s16x8*)&As[half][(wm * 64 + s * 16 + r16) * 32 + k8];
        bfv[s] = *(const s16x8*)&Bs[half][(wn * 64 + s * 16 + r16) * 32 + k8];
      }
#pragma unroll
      for (int sm = 0; sm < 4; sm++)
#pragma unroll
        for (int sn = 0; sn < 4; sn++)
          acc[sm][sn] = __builtin_amdgcn_mfma_f32_16x16x32_bf16(af[sm], bfv[sn], acc[sm][sn], 0, 0, 0);
    }
  }
  int quad = lane >> 4, col = lane & 15;
#pragma unroll
  for (int sn = 0; sn < 4; sn++) {
    int gn = m0 + wn * 64 + sn * 16 + col;          // key index m
#pragma unroll
    for (int sm = 0; sm < 4; sm++) {
      int gmb = n0 + wm * 64 + sm * 16 + quad * 4;  // query index n
#pragma unroll
      for (int i = 0; i < 4; i++) {
        int gm = gmb + i;
        if (gm < NN && gn < NN)
          att[((size_t)bz * NN + gm) * ATTS + gn] = acc[sm][sn][i] * SCALE_;
      }
    }
  }
}

// ---------------- per (b,n): mask-mix + relu + head-proj + softmax -> P -----
// P[b][h][n][KPAD] bf16, zero-padded for m in [197,224).
__global__ __launch_bounds__(256) void k_softmax_p(const float* __restrict__ att,
                                                   const float* __restrict__ masks,
                                                   const float* __restrict__ mproj,
                                                   const float* __restrict__ mbase,
                                                   const float* __restrict__ hpw,
                                                   const float* __restrict__ hpb,
                                                   u16* __restrict__ P) {
  __shared__ float S[12][200];
  __shared__ float hpw_s[144], hpb_s[12], mp_s[36], mb_s[12];
  int t = threadIdx.x;
  int n = blockIdx.x, b = blockIdx.y;

  if (t < 144) hpw_s[t] = hpw[t];
  if (t < 36) mp_s[t] = mproj[t];
  if (t < 12) { hpb_s[t] = hpb[t]; mb_s[t] = mbase[t]; }
  __syncthreads();

  if (t < NN) {
    int m = t;
    float a0 = att[((size_t)(b * 2 + 0) * NN + n) * ATTS + m];
    float a1 = att[((size_t)(b * 2 + 1) * NN + n) * ATTS + m];
    const float* mk = masks + ((size_t)n * NN + m) * 3;
    float l0 = mk[0], l1 = mk[1], l2 = mk[2];
    float pre[12];
#pragma unroll
    for (int h = 0; h < 12; h++) {
      float wgt = mb_s[h] + l0 * mp_s[h] + l1 * mp_s[12 + h] + l2 * mp_s[24 + h];
      float v = (h < 6 ? a0 : a1) * wgt;
      pre[h] = v > 0.f ? v : 0.f;
    }
#pragma unroll
    for (int h2 = 0; h2 < 12; h2++) {
      float s = hpb_s[h2];
#pragma unroll
      for (int h = 0; h < 12; h++) s += pre[h] * hpw_s[h * 12 + h2];
      S[h2][m] = s;
    }
  }
  __syncthreads();

  {  // softmax per head, 16-lane groups (R5-verified pattern)
    int g = t >> 4, l16 = t & 15;
    if (g < 12) {
      float mx = -1e30f;
      for (int m = l16; m < NN; m += 16) mx = fmaxf(mx, S[g][m]);
#pragma unroll
      for (int off = 8; off; off >>= 1) mx = fmaxf(mx, __shfl_xor(mx, off, 16));
      float sum = 0.f;
      for (int m = l16; m < NN; m += 16) {
        float e = __expf(S[g][m] - mx);
        S[g][m] = e;
        sum += e;
      }
#pragma unroll
      for (int off = 8; off; off >>= 1) sum += __shfl_xor(sum, off, 16);
      float inv = 1.f / sum;
      for (int m = l16; m < NN; m += 16) S[g][m] *= inv;
    }
  }
  __syncthreads();

  // write P rows (bf16), zero tail m in [197,224)
  for (int c4 = t; c4 < 12 * KPAD / 4; c4 += 256) {
    int idx = c4 * 4;
    int h = idx / KPAD, m = idx - h * KPAD;
    ushort4 u;
    u.x = f2bf(m + 0 < NN ? S[h][m + 0] : 0.f);
    u.y = f2bf(m + 1 < NN ? S[h][m + 1] : 0.f);
    u.z = f2bf(m + 2 < NN ? S[h][m + 2] : 0.f);
    u.w = f2bf(m + 3 < NN ? S[h][m + 3] : 0.f);
    *(ushort4*)(P + ((size_t)(b * HH + h) * NN + n) * KPAD + m) = u;
  }
}

// ---------------- PV via MFMA: O[b,n,h,d] = sum_m P[b,h,n,m] V[b,m,h,d] -----
// One block per (n-tile 128, b*12+h). M=197(n) N=64(d) K=224(m).
// BK=64 (3 full steps + one 32 tail) -> 4 barriers instead of 7.
__global__ __launch_bounds__(256) void k_pv(const u16* __restrict__ P,
                                            const u16* __restrict__ qkv,
                                            u16* __restrict__ aout) {
  __shared__ u16 As[2][128 * 32];  // P rows [n][32 m] per half
  __shared__ u16 Bs[2][64 * 32];   // VT [d][32 m] per half
  int t = threadIdx.x;
  int w = t >> 6, lane = t & 63;
  int bh = blockIdx.y, b = bh / HH, h = bh - b * HH;
  int n0 = blockIdx.x * 128;

  f32x4 acc[2][4];
#pragma unroll
  for (int i = 0; i < 2; i++)
#pragma unroll
    for (int j = 0; j < 4; j++)
#pragma unroll
      for (int e = 0; e < 4; e++) acc[i][j][e] = 0.f;

  int lrow4 = lane >> 2, lkc = (lane & 3) * 8;
  int vml = t & 31, vd0 = (t >> 5) * 8;    // B-staging mapping

  for (int k0 = 0; k0 < KPAD; k0 += 64) {
    int nh = (KPAD - k0 >= 64) ? 2 : 1;
    for (int half = 0; half < nh; half++) {
      int kk = k0 + half * 32;
      // A: P rows via gl_lds16
#pragma unroll
      for (int rc = 0; rc < 2; rc++) {
        int c = w + rc * 4;
        int row = c * 16 + lrow4;
        int gn = n0 + row; if (gn > NN - 1) gn = NN - 1;
        gl_lds16(P + ((size_t)bh * NN + gn) * KPAD + kk + lkc, &As[half][c * 512]);
      }
      // B: V rows -> transposed LDS [d][m]
      {
        int m = kk + vml;
        u16 v8[8];
        if (m < NN) {
          const ushort4* vp = (const ushort4*)(qkv + (size_t)(b * NN + m) * QKVN + (4 + h) * DD + vd0);
          ushort4 lo = vp[0], hi = vp[1];
          v8[0] = lo.x; v8[1] = lo.y; v8[2] = lo.z; v8[3] = lo.w;
          v8[4] = hi.x; v8[5] = hi.y; v8[6] = hi.z; v8[7] = hi.w;
        } else {
#pragma unroll
          for (int j = 0; j < 8; j++) v8[j] = 0;
        }
#pragma unroll
        for (int j = 0; j < 8; j++) Bs[half][(vd0 + j) * 32 + vml] = v8[j];
      }
    }
    __syncthreads();
    int r16 = lane & 15, k8 = (lane >> 4) * 8;
    for (int half = 0; half < nh; half++) {
      s16x8 af[2], bfv[4];
#pragma unroll
      for (int s = 0; s < 2; s++)
        af[s] = *(const s16x8*)&As[half][(w * 32 + s * 16 + r16) * 32 + k8];
#pragma unroll
      for (int s = 0; s < 4; s++)
        bfv[s] = *(const s16x8*)&Bs[half][(s * 16 + r16) * 32 + k8];
#pragma unroll
      for (int sm = 0; sm < 2; sm++)
#pragma unroll
        for (int sn = 0; sn < 4; sn++)
          acc[sm][sn] = __builtin_amdgcn_mfma_f32_16x16x32_bf16(af[sm], bfv[sn], acc[sm][sn], 0, 0, 0);
    }
    __syncthreads();
  }
  int quad = lane >> 4, col = lane & 15;
#pragma unroll
  for (int sn = 0; sn < 4; sn++) {
    int gd = sn * 16 + col;                         // d
#pragma unroll
    for (int sm = 0; sm < 2; sm++) {
      int gnb = n0 + w * 32 + sm * 16 + quad * 4;   // n
#pragma unroll
      for (int i = 0; i < 4; i++) {
        int gn = gnb + i;
        if (gn < NN)
          aout[(size_t)(b * NN + gn) * CC + h * DD + gd] = f2bf(acc[sm][sn][i]);
      }
    }
  }
}

extern "C" void kernel_launch(void* const* d_in, const int* in_sizes, int n_in,
                              void* d_out, int out_size, void* d_ws, size_t ws_size,
                              hipStream_t stream) {
  const float* x     = (const float*)d_in[0];
  const float* qkv_w = (const float*)d_in[1];
  const float* qkv_b = (const float*)d_in[2];
  const float* masks = (const float*)d_in[3];
  const float* mproj = (const float*)d_in[4];
  const float* mbase = (const float*)d_in[5];
  const float* hpw   = (const float*)d_in[6];
  const float* hpb   = (const float*)d_in[7];
  const float* projw = (const float*)d_in[8];
  const float* projb = (const float*)d_in[9];

  char* ws = (char*)d_ws;
  size_t off = 0;
  auto alloc = [&](size_t bytes) {
    char* p = ws + off; off = (off + bytes + 255) & ~(size_t)255; return p;
  };
  // region1: xbf (19.4MB) -> att (21.0MB) -> aout (19.4MB), disjoint lifetimes
  char*  r1   = alloc((size_t)BB * 2 * NN * ATTS * 4);
  u16*   xbf  = (u16*)r1;
  float* att  = (float*)r1;
  u16*   aout = (u16*)r1;
  u16*   qkv  = (u16*)alloc((size_t)MROWS * QKVN * 2);          // 25.8 MB
  u16*   P    = (u16*)alloc((size_t)BB * HH * NN * KPAD * 2);   // 67.8 MB
  u16*   wt1  = (u16*)alloc((size_t)QKVN * CC * 2);             //  1.6 MB
  u16*   wt2  = (u16*)alloc((size_t)CC * CC * 2);               //  1.2 MB

  int n8 = MROWS * CC / 8;
  k_cvt_x<<<(n8 + 255) / 256, 256, 0, stream>>>(x, xbf, n8);
  k_transpose<<<dim3(QKVN / 32, CC / 32), 256, 0, stream>>>(qkv_w, wt1, CC, QKVN);
  k_transpose<<<dim3(CC / 32, CC / 32), 256, 0, stream>>>(projw, wt2, CC, CC);
  // qkv = x @ qkv_w + qkv_b  (bf16 out)
  k_gemm_bt<<<dim3(QKVN / 128, (MROWS + 127) / 128), 256, 0, stream>>>(
      xbf, wt1, qkv_b, qkv, MROWS, QKVN, CC, 1);
  // att[bg][n][m] = SCALE * q.k
  k_qk<<<dim3(2, 2, BB * 2), 256, 0, stream>>>(qkv, att);
  // P[b][h][n][m] (bf16, softmaxed)
  k_softmax_p<<<dim3(NN, BB), 256, 0, stream>>>(att, masks, mproj, mbase, hpw, hpb, P);
  // aout[b][n][h*64+d] = P @ V
  k_pv<<<dim3(2, BB * HH), 256, 0, stream>>>(P, qkv, aout);
  // out = aout @ proj_w + proj_b  (f32 out)
  k_gemm_bt<<<dim3(CC / 128, (MROWS + 127) / 128), 256, 0, stream>>>(
      aout, wt2, projb, d_out, MROWS, CC, CC, 0);
}

// Round 9
// 292.244 us; speedup vs baseline: 5.9088x; 1.0204x over previous
//
#include <hip/hip_runtime.h>
#include <cstdint>
#include <cstddef>

// Problem constants
#define BB   64
#define NN   197
#define CC   768
#define HH   12
#define THD  16          // TOTAL_HEADS
#define DD   64
#define MROWS (BB*NN)    // 12608
#define QKVN (THD*DD)    // 1024
#define SCALE_ 0.125f
#define ATTS 208         // att row stride (f32)
#define KPAD 224         // P row k-padding (7*32)

typedef unsigned short u16;
typedef __attribute__((ext_vector_type(2))) float f32x2;
typedef __attribute__((ext_vector_type(4))) float f32x4;
typedef __attribute__((ext_vector_type(8))) short s16x8;
typedef __attribute__((address_space(1))) unsigned int as1_u32;
typedef __attribute__((address_space(3))) unsigned int as3_u32;

__device__ __forceinline__ float bf2f(u16 u) {
  union { unsigned int i; float f; } x; x.i = ((unsigned int)u) << 16; return x.f;
}
__device__ __forceinline__ u16 f2bf(float f) {
  unsigned int x = __builtin_bit_cast(unsigned int, f);
  unsigned int r = (x + 0x7fffu + ((x >> 16) & 1u)) >> 16;   // RNE
  return (u16)r;
}
__device__ __forceinline__ void gl_lds16(const u16* g, u16* l) {
  __builtin_amdgcn_global_load_lds((const as1_u32*)g, (as3_u32*)l, 16, 0, 0);
}

// ---------------- x (f32) -> bf16, 8 elems/thread ---------------------------
__global__ __launch_bounds__(256) void k_cvt_x(const float* __restrict__ src,
                                               u16* __restrict__ dst, int n8) {
  int i = blockIdx.x * 256 + threadIdx.x;
  if (i >= n8) return;
  const float4* s = (const float4*)src;
  float4 a = s[2 * i], b = s[2 * i + 1];
  ushort4 lo, hi;
  lo.x = f2bf(a.x); lo.y = f2bf(a.y); lo.z = f2bf(a.z); lo.w = f2bf(a.w);
  hi.x = f2bf(b.x); hi.y = f2bf(b.y); hi.z = f2bf(b.z); hi.w = f2bf(b.w);
  ((ushort4*)dst)[2 * i] = lo;
  ((ushort4*)dst)[2 * i + 1] = hi;
}

// ---------------- weight transpose+convert f32 (R,Ccol) -> bf16 (Ccol,R) ----
__global__ __launch_bounds__(256) void k_transpose(const float* __restrict__ in,
                                                   u16* __restrict__ out,
                                                   int R, int Ccol) {
  __shared__ u16 tile[32][33];
  int c0 = blockIdx.x * 32, r0 = blockIdx.y * 32;
  int tx = threadIdx.x & 31, ty = threadIdx.x >> 5;
#pragma unroll
  for (int i = 0; i < 32; i += 8) {
    int r = r0 + ty + i, c = c0 + tx;
    tile[ty + i][tx] = (r < R && c < Ccol) ? f2bf(in[(size_t)r * Ccol + c]) : (u16)0;
  }
  __syncthreads();
#pragma unroll
  for (int i = 0; i < 32; i += 8) {
    int cc = c0 + ty + i, rr = r0 + tx;
    if (cc < Ccol && rr < R) out[(size_t)cc * R + rr] = tile[tx][ty + i];
  }
}

// ---------------- bf16 MFMA GEMM: C[M,N] = A[M,K] * Bt[N,K]^T + bias --------
// 128x128 tile, 4 waves (2x2), 16x16x32 MFMA, BK=64 (32 MFMA/barrier).
// Grid: x = m-tile (fast-varying) so each XCD owns disjoint A rows; B is
// small and L2-resident per XCD.
__global__ __launch_bounds__(256) void k_gemm_bt(const u16* __restrict__ A,
                                                 const u16* __restrict__ Bt,
                                                 const float* __restrict__ bias,
                                                 void* __restrict__ Cout,
                                                 int M, int Nn, int K,
                                                 int write_bf16) {
  __shared__ u16 As[2][128 * 32];
  __shared__ u16 Bs[2][128 * 32];
  int t = threadIdx.x;
  int w = t >> 6, lane = t & 63;
  int m0 = blockIdx.x * 128, n0 = blockIdx.y * 128;   // R9: m-tile fastest
  int wm = w >> 1, wn = w & 1;

  f32x4 acc[4][4];
#pragma unroll
  for (int i = 0; i < 4; i++)
#pragma unroll
    for (int j = 0; j < 4; j++)
#pragma unroll
      for (int e = 0; e < 4; e++) acc[i][j][e] = 0.f;

  int lrow4 = lane >> 2;       // 0..15
  int lkc = (lane & 3) * 8;    // 0,8,16,24

  for (int k0 = 0; k0 < K; k0 += 64) {
#pragma unroll
    for (int half = 0; half < 2; half++) {
      int kk = k0 + half * 32;
#pragma unroll
      for (int rc = 0; rc < 2; rc++) {
        int c = w + rc * 4;                 // chunk 0..7 => rows c*16..c*16+15
        int row = c * 16 + lrow4;
        int ga = m0 + row; if (ga >= M) ga = M - 1;
        gl_lds16(A + (size_t)ga * K + kk + lkc, &As[half][c * 512]);
        gl_lds16(Bt + (size_t)(n0 + row) * K + kk + lkc, &Bs[half][c * 512]);
      }
    }
    __syncthreads();
    int r16 = lane & 15, k8 = (lane >> 4) * 8;
#pragma unroll
    for (int half = 0; half < 2; half++) {
      s16x8 af[4], bfv[4];
#pragma unroll
      for (int s = 0; s < 4; s++) {
        af[s]  = *(const s16x8*)&As[half][(wm * 64 + s * 16 + r16) * 32 + k8];
        bfv[s] = *(const s16x8*)&Bs[half][(wn * 64 + s * 16 + r16) * 32 + k8];
      }
#pragma unroll
      for (int sm = 0; sm < 4; sm++)
#pragma unroll
        for (int sn = 0; sn < 4; sn++)
          acc[sm][sn] = __builtin_amdgcn_mfma_f32_16x16x32_bf16(af[sm], bfv[sn], acc[sm][sn], 0, 0, 0);
    }
    __syncthreads();
  }
  // epilogue: C/D layout col=lane&15, row=(lane>>4)*4+i
  u16*   Cb = (u16*)Cout;
  float* Cf = (float*)Cout;
  int quad = lane >> 4, col = lane & 15;
#pragma unroll
  for (int sn = 0; sn < 4; sn++) {
    int gn = n0 + wn * 64 + sn * 16 + col;
    float bv = bias[gn];
#pragma unroll
    for (int sm = 0; sm < 4; sm++) {
      int gmb = m0 + wm * 64 + sm * 16 + quad * 4;
#pragma unroll
      for (int i = 0; i < 4; i++) {
        int gm = gmb + i;
        if (gm < M) {
          float v = acc[sm][sn][i] + bv;
          if (write_bf16) Cb[(size_t)gm * Nn + gn] = f2bf(v);
          else            Cf[(size_t)gm * Nn + gn] = v;
        }
      }
    }
  }
}

// ---------------- QK^T logits via MFMA: att[bg][n][m] = SCALE * q_n . k_m ---
// One block per (n-tile 128, m-tile 128, b*2+g). K=64: ONE barrier, 32 MFMA.
__global__ __launch_bounds__(256) void k_qk(const u16* __restrict__ qkv,
                                            float* __restrict__ att) {
  __shared__ u16 As[2][128 * 32];
  __shared__ u16 Bs[2][128 * 32];
  int t = threadIdx.x;
  int w = t >> 6, lane = t & 63;
  int bz = blockIdx.z, b = bz >> 1, g = bz & 1;
  int n0 = blockIdx.x * 128;     // Q rows
  int m0 = blockIdx.y * 128;     // K rows
  int wm = w >> 1, wn = w & 1;

  f32x4 acc[4][4];
#pragma unroll
  for (int i = 0; i < 4; i++)
#pragma unroll
    for (int j = 0; j < 4; j++)
#pragma unroll
      for (int e = 0; e < 4; e++) acc[i][j][e] = 0.f;

  int lrow4 = lane >> 2, lkc = (lane & 3) * 8;

#pragma unroll
  for (int half = 0; half < 2; half++) {
    int kk = half * 32;
#pragma unroll
    for (int rc = 0; rc < 2; rc++) {
      int c = w + rc * 4;
      int row = c * 16 + lrow4;
      int nq = n0 + row; if (nq > NN - 1) nq = NN - 1;
      int mk = m0 + row; if (mk > NN - 1) mk = NN - 1;
      gl_lds16(qkv + (size_t)(b * NN + nq) * QKVN + g * DD + kk + lkc, &As[half][c * 512]);
      gl_lds16(qkv + (size_t)(b * NN + mk) * QKVN + 2 * DD + g * DD + kk + lkc, &Bs[half][c * 512]);
    }
  }
  __syncthreads();
  {
    int r16 = lane & 15, k8 = (lane >> 4) * 8;
#pragma unroll
    for (int half = 0; half < 2; half++) {
      s16x8 af[4], bfv[4];
#pragma unroll
      for (int s = 0; s < 4; s++) {
        af[s]  = *(const s16x8*)&As[half][(wm * 64 + s * 16 + r16) * 32 + k8];
        bfv[s] = *(const s16x8*)&Bs[half][(wn * 64 + s * 16 + r16) * 32 + k8];
      }
#pragma unroll
      for (int sm = 0; sm < 4; sm++)
#pragma unroll
        for (int sn = 0; sn < 4; sn++)
          acc[sm][sn] = __builtin_amdgcn_mfma_f32_16x16x32_bf16(af[sm], bfv[sn], acc[sm][sn], 0, 0, 0);
    }
  }
  int quad = lane >> 4, col = lane & 15;
#pragma unroll
  for (int sn = 0; sn < 4; sn++) {
    int gn = m0 + wn * 64 + sn * 16 + col;          // key index m
#pragma unroll
    for (int sm = 0; sm < 4; sm++) {
      int gmb = n0 + wm * 64 + sm * 16 + quad * 4;  // query index n
#pragma unroll
      for (int i = 0; i < 4; i++) {
        int gm = gmb + i;
        if (gm < NN && gn < NN)
          att[((size_t)bz * NN + gm) * ATTS + gn] = acc[sm][sn][i] * SCALE_;
      }
    }
  }
}

// ---------------- per (b,n): mask-mix + relu + head-proj + softmax -> P -----
// R9: f32x2 packed math; S[12][KPAD] tail-zeroed; f32x4 LDS reads in P-write.
__global__ __launch_bounds__(256) void k_softmax_p(const float* __restrict__ att,
                                                   const float* __restrict__ masks,
                                                   const float* __restrict__ mproj,
                                                   const float* __restrict__ mbase,
                                                   const float* __restrict__ hpw,
                                                   const float* __restrict__ hpb,
                                                   u16* __restrict__ P) {
  __shared__ float S[12][KPAD];          // 10.5 KB, tail [197,224) zeroed
  __shared__ f32x2 hpw_s[72];            // [h][k], k = h2-pair 0..5
  __shared__ f32x2 mp_s[18];             // [l][k], k = h-pair
  __shared__ f32x2 mb_s[6], hpb_s[6];
  int t = threadIdx.x;
  int n = blockIdx.x, b = blockIdx.y;

  if (t < 72) hpw_s[t] = ((const f32x2*)hpw)[t];
  if (t < 18) mp_s[t] = ((const f32x2*)mproj)[t];
  if (t < 6) { mb_s[t] = ((const f32x2*)mbase)[t]; hpb_s[t] = ((const f32x2*)hpb)[t]; }
  __syncthreads();

  if (t < NN) {
    int m = t;
    float a0 = att[((size_t)(b * 2 + 0) * NN + n) * ATTS + m];
    float a1 = att[((size_t)(b * 2 + 1) * NN + n) * ATTS + m];
    const float* mk = masks + ((size_t)n * NN + m) * 3;
    float l0 = mk[0], l1 = mk[1], l2 = mk[2];
    f32x2 pre2[6];
#pragma unroll
    for (int k = 0; k < 6; k++) {
      f32x2 wv = mb_s[k] + l0 * mp_s[k] + l1 * mp_s[6 + k] + l2 * mp_s[12 + k];
      float av = (k < 3) ? a0 : a1;
      f32x2 v = wv * av;
      pre2[k].x = v.x > 0.f ? v.x : 0.f;
      pre2[k].y = v.y > 0.f ? v.y : 0.f;
    }
    f32x2 s2[6];
#pragma unroll
    for (int k = 0; k < 6; k++) s2[k] = hpb_s[k];
#pragma unroll
    for (int h = 0; h < 12; h++) {
      float p = (h & 1) ? pre2[h >> 1].y : pre2[h >> 1].x;
#pragma unroll
      for (int k = 0; k < 6; k++) s2[k] += p * hpw_s[h * 6 + k];
    }
#pragma unroll
    for (int k = 0; k < 6; k++) {
      S[2 * k][m] = s2[k].x;
      S[2 * k + 1][m] = s2[k].y;
    }
  } else if (t < KPAD) {
#pragma unroll
    for (int h = 0; h < 12; h++) S[h][t] = 0.f;
  }
  __syncthreads();

  {  // softmax per head, 16-lane groups (verified pattern)
    int g = t >> 4, l16 = t & 15;
    if (g < 12) {
      float mx = -1e30f;
      for (int m = l16; m < NN; m += 16) mx = fmaxf(mx, S[g][m]);
#pragma unroll
      for (int off = 8; off; off >>= 1) mx = fmaxf(mx, __shfl_xor(mx, off, 16));
      float sum = 0.f;
      for (int m = l16; m < NN; m += 16) {
        float e = __expf(S[g][m] - mx);
        S[g][m] = e;
        sum += e;
      }
#pragma unroll
      for (int off = 8; off; off >>= 1) sum += __shfl_xor(sum, off, 16);
      float inv = 1.f / sum;
      for (int m = l16; m < NN; m += 16) S[g][m] *= inv;
    }
  }
  __syncthreads();

  // write P rows (bf16): 12*224/4 = 672 f32x4 chunks, no guards (tail = 0)
  for (int c4 = t; c4 < 672; c4 += 256) {
    int h = c4 / 56;                 // 56 chunks per head row
    int m = (c4 - h * 56) * 4;
    f32x4 v = *(const f32x4*)&S[h][m];
    ushort4 u;
    u.x = f2bf(v.x); u.y = f2bf(v.y); u.z = f2bf(v.z); u.w = f2bf(v.w);
    *(ushort4*)(P + ((size_t)(b * HH + h) * NN + n) * KPAD + m) = u;
  }
}

// ---------------- PV via MFMA: O[b,n,h,d] = sum_m P[b,h,n,m] V[b,m,h,d] -----
// One block per (n-tile 128, b*12+h). M=197(n) N=64(d) K=224(m). BK=64.
__global__ __launch_bounds__(256) void k_pv(const u16* __restrict__ P,
                                            const u16* __restrict__ qkv,
                                            u16* __restrict__ aout) {
  __shared__ u16 As[2][128 * 32];  // P rows [n][32 m] per half
  __shared__ u16 Bs[2][64 * 32];   // VT [d][32 m] per half
  int t = threadIdx.x;
  int w = t >> 6, lane = t & 63;
  int bh = blockIdx.y, b = bh / HH, h = bh - b * HH;
  int n0 = blockIdx.x * 128;

  f32x4 acc[2][4];
#pragma unroll
  for (int i = 0; i < 2; i++)
#pragma unroll
    for (int j = 0; j < 4; j++)
#pragma unroll
      for (int e = 0; e < 4; e++) acc[i][j][e] = 0.f;

  int lrow4 = lane >> 2, lkc = (lane & 3) * 8;
  int vml = t & 31, vd0 = (t >> 5) * 8;    // B-staging mapping

  for (int k0 = 0; k0 < KPAD; k0 += 64) {
    int nh = (KPAD - k0 >= 64) ? 2 : 1;
    for (int half = 0; half < nh; half++) {
      int kk = k0 + half * 32;
      // A: P rows via gl_lds16
#pragma unroll
      for (int rc = 0; rc < 2; rc++) {
        int c = w + rc * 4;
        int row = c * 16 + lrow4;
        int gn = n0 + row; if (gn > NN - 1) gn = NN - 1;
        gl_lds16(P + ((size_t)bh * NN + gn) * KPAD + kk + lkc, &As[half][c * 512]);
      }
      // B: V rows -> transposed LDS [d][m]
      {
        int m = kk + vml;
        u16 v8[8];
        if (m < NN) {
          const ushort4* vp = (const ushort4*)(qkv + (size_t)(b * NN + m) * QKVN + (4 + h) * DD + vd0);
          ushort4 lo = vp[0], hi = vp[1];
          v8[0] = lo.x; v8[1] = lo.y; v8[2] = lo.z; v8[3] = lo.w;
          v8[4] = hi.x; v8[5] = hi.y; v8[6] = hi.z; v8[7] = hi.w;
        } else {
#pragma unroll
          for (int j = 0; j < 8; j++) v8[j] = 0;
        }
#pragma unroll
        for (int j = 0; j < 8; j++) Bs[half][(vd0 + j) * 32 + vml] = v8[j];
      }
    }
    __syncthreads();
    int r16 = lane & 15, k8 = (lane >> 4) * 8;
    for (int half = 0; half < nh; half++) {
      s16x8 af[2], bfv[4];
#pragma unroll
      for (int s = 0; s < 2; s++)
        af[s] = *(const s16x8*)&As[half][(w * 32 + s * 16 + r16) * 32 + k8];
#pragma unroll
      for (int s = 0; s < 4; s++)
        bfv[s] = *(const s16x8*)&Bs[half][(s * 16 + r16) * 32 + k8];
#pragma unroll
      for (int sm = 0; sm < 2; sm++)
#pragma unroll
        for (int sn = 0; sn < 4; sn++)
          acc[sm][sn] = __builtin_amdgcn_mfma_f32_16x16x32_bf16(af[sm], bfv[sn], acc[sm][sn], 0, 0, 0);
    }
    __syncthreads();
  }
  int quad = lane >> 4, col = lane & 15;
#pragma unroll
  for (int sn = 0; sn < 4; sn++) {
    int gd = sn * 16 + col;                         // d
#pragma unroll
    for (int sm = 0; sm < 2; sm++) {
      int gnb = n0 + w * 32 + sm * 16 + quad * 4;   // n
#pragma unroll
      for (int i = 0; i < 4; i++) {
        int gn = gnb + i;
        if (gn < NN)
          aout[(size_t)(b * NN + gn) * CC + h * DD + gd] = f2bf(acc[sm][sn][i]);
      }
    }
  }
}

extern "C" void kernel_launch(void* const* d_in, const int* in_sizes, int n_in,
                              void* d_out, int out_size, void* d_ws, size_t ws_size,
                              hipStream_t stream) {
  const float* x     = (const float*)d_in[0];
  const float* qkv_w = (const float*)d_in[1];
  const float* qkv_b = (const float*)d_in[2];
  const float* masks = (const float*)d_in[3];
  const float* mproj = (const float*)d_in[4];
  const float* mbase = (const float*)d_in[5];
  const float* hpw   = (const float*)d_in[6];
  const float* hpb   = (const float*)d_in[7];
  const float* projw = (const float*)d_in[8];
  const float* projb = (const float*)d_in[9];

  char* ws = (char*)d_ws;
  size_t off = 0;
  auto alloc = [&](size_t bytes) {
    char* p = ws + off; off = (off + bytes + 255) & ~(size_t)255; return p;
  };
  // region1: xbf (19.4MB) -> att (21.0MB) -> aout (19.4MB), disjoint lifetimes
  char*  r1   = alloc((size_t)BB * 2 * NN * ATTS * 4);
  u16*   xbf  = (u16*)r1;
  float* att  = (float*)r1;
  u16*   aout = (u16*)r1;
  u16*   qkv  = (u16*)alloc((size_t)MROWS * QKVN * 2);          // 25.8 MB
  u16*   P    = (u16*)alloc((size_t)BB * HH * NN * KPAD * 2);   // 67.8 MB
  u16*   wt1  = (u16*)alloc((size_t)QKVN * CC * 2);             //  1.6 MB
  u16*   wt2  = (u16*)alloc((size_t)CC * CC * 2);               //  1.2 MB

  int n8 = MROWS * CC / 8;
  k_cvt_x<<<(n8 + 255) / 256, 256, 0, stream>>>(x, xbf, n8);
  k_transpose<<<dim3(QKVN / 32, CC / 32), 256, 0, stream>>>(qkv_w, wt1, CC, QKVN);
  k_transpose<<<dim3(CC / 32, CC / 32), 256, 0, stream>>>(projw, wt2, CC, CC);
  // qkv = x @ qkv_w + qkv_b  (bf16 out); grid: m-tile fastest (XCD locality)
  k_gemm_bt<<<dim3((MROWS + 127) / 128, QKVN / 128), 256, 0, stream>>>(
      xbf, wt1, qkv_b, qkv, MROWS, QKVN, CC, 1);
  // att[bg][n][m] = SCALE * q.k
  k_qk<<<dim3(2, 2, BB * 2), 256, 0, stream>>>(qkv, att);
  // P[b][h][n][m] (bf16, softmaxed)
  k_softmax_p<<<dim3(NN, BB), 256, 0, stream>>>(att, masks, mproj, mbase, hpw, hpb, P);
  // aout[b][n][h*64+d] = P @ V
  k_pv<<<dim3(2, BB * HH), 256, 0, stream>>>(P, qkv, aout);
  // out = aout @ proj_w + proj_b  (f32 out); grid: m-tile fastest
  k_gemm_bt<<<dim3((MROWS + 127) / 128, CC / 128), 256, 0, stream>>>(
      aout, wt2, projb, d_out, MROWS, CC, CC, 0);
}